// Round 8
// baseline (356.427 us; speedup 1.0000x reference)
//
#include <hip/hip_runtime.h>
#include <cstdint>
#include <cstddef>

// ---------------------------------------------------------------------------
// MultiHeadSelfAttention: B=4, S=2048, D=1024, H=16, Hd=64. f32 in/out.
// R13: GEMMs use T3's minimum 2-phase LDS double-buffer at BK=32:
//   stage(buf[t+1]) async gl2lds -> compute(buf[t]) -> ONE barrier.
// Loads fly under the same block's MFMA; barrier drain happens after
// compute. Identical tile geometry + MFMA order as R11 (bit-identical).
// qkv: 4-wave blocks (32 KB LDS, 5 blocks/CU); out_proj: 8-wave (grid-
// limited, LDS doubling free). Attn = proven R10 version, untouched.
// ---------------------------------------------------------------------------

typedef unsigned short ushortT;
typedef __bf16 bf16x8 __attribute__((ext_vector_type(8)));
typedef _Float16 f16x4 __attribute__((ext_vector_type(4)));
typedef float f32x4 __attribute__((ext_vector_type(4)));
typedef unsigned int u32x2 __attribute__((ext_vector_type(2)));
typedef unsigned short us4 __attribute__((ext_vector_type(4)));
typedef unsigned short us8 __attribute__((ext_vector_type(8)));

#define S_LEN 2048
#define NB 4
#define NH 16
#define HD 64
#define DMODEL 1024
#define MTOT 8192   // NB * S_LEN
#define WSZ 1048576 // DMODEL * DMODEL

#define AS1 __attribute__((address_space(1)))
#define AS3 __attribute__((address_space(3)))

__device__ __forceinline__ ushortT f2b(float f) {  // round-to-nearest-even
  unsigned x = __builtin_bit_cast(unsigned, f);
  x += 0x7fffu + ((x >> 16) & 1u);
  return (ushortT)(x >> 16);
}

// pack two f32 (bit patterns) -> two RNE bf16 in one dword (lo in low half)
__device__ __forceinline__ unsigned rne_pack(unsigned lo, unsigned hi) {
  lo += 0x7fffu + ((lo >> 16) & 1u);
  hi += 0x7fffu + ((hi >> 16) & 1u);
  return __builtin_amdgcn_perm(hi, lo, 0x07060302u);
}

__device__ __forceinline__ f32x4 mfma_bf16(bf16x8 a, bf16x8 b, f32x4 c) {
  return __builtin_amdgcn_mfma_f32_16x16x32_bf16(a, b, c, 0, 0, 0);
}
__device__ __forceinline__ f32x4 mfma16_f16(f16x4 a, f16x4 b, f32x4 c) {
  return __builtin_amdgcn_mfma_f32_16x16x16f16(a, b, c, 0, 0, 0);
}

// async 16B global->LDS; lds dst is wave-uniform base, lane i lands at +16*i
__device__ __forceinline__ void gl2lds16(const ushortT* g, ushortT* l) {
  __builtin_amdgcn_global_load_lds((const AS1 void*)g, (AS3 void*)l, 16, 0, 0);
}

// ---------------------------------------------------------------------------
// f32 -> bf16 converters (elementwise, 8 elems/thread).
// ---------------------------------------------------------------------------
__global__ __launch_bounds__(256) void convert_w_kernel(
    const float* __restrict__ wq, const float* __restrict__ wk,
    const float* __restrict__ wv, const float* __restrict__ wo,
    ushortT* __restrict__ dst) {
  const float* s;
  switch (blockIdx.y) {
    case 0: s = wq; break;
    case 1: s = wk; break;
    case 2: s = wv; break;
    default: s = wo; break;
  }
  ushortT* d = dst + (size_t)blockIdx.y * WSZ;
  const size_t i = ((size_t)blockIdx.x * 256 + threadIdx.x) * 8;
  uint4 w0 = *(const uint4*)(s + i);
  uint4 w1 = *(const uint4*)(s + i + 4);
  uint4 pk;
  pk.x = rne_pack(w0.x, w0.y);
  pk.y = rne_pack(w0.z, w0.w);
  pk.z = rne_pack(w1.x, w1.y);
  pk.w = rne_pack(w1.z, w1.w);
  *(uint4*)(d + i) = pk;
}

__global__ __launch_bounds__(256) void convert_x_kernel(
    const float* __restrict__ vals, const float* __restrict__ keys,
    const float* __restrict__ qry, ushortT* __restrict__ dst) {
  const float* s;
  switch (blockIdx.y) {
    case 0: s = vals; break;
    case 1: s = keys; break;
    default: s = qry; break;
  }
  ushortT* d = dst + (size_t)blockIdx.y * ((size_t)MTOT * DMODEL);
  const size_t i = ((size_t)blockIdx.x * 256 + threadIdx.x) * 8;
  uint4 w0 = *(const uint4*)(s + i);
  uint4 w1 = *(const uint4*)(s + i + 4);
  uint4 pk;
  pk.x = rne_pack(w0.x, w0.y);
  pk.y = rne_pack(w0.z, w0.w);
  pk.z = rne_pack(w1.x, w1.y);
  pk.w = rne_pack(w1.z, w1.w);
  *(uint4*)(d + i) = pk;
}

// ---------------------------------------------------------------------------
// 2-phase double-buffered GEMM: C(M,N) = A(M,K) * W(N,K)^T (+bias), A bf16.
// Grid (64,8[,z]): by = blockIdx.x (A rows), bx = blockIdx.y (W cols) so all
// 8 bx-blocks of a panel share one XCD's L2.
// Per iter: stage next [128][32] tiles into the spare buffer (async gl2lds),
// compute current buffer, one barrier. Tile geometry + MFMA order = R11.
// NW=4: 2x2 waves of 64x64 subtiles; NW=8: 2x4 waves of 64x32.
// VT_MODE=1: scatter-store f16 into Vt layout (B,H,64,S), 4-wide along S.
// ---------------------------------------------------------------------------
template <int VT_MODE, bool OUT_F32, bool HAS_BIAS, int NW>
__device__ __forceinline__ void gemm_bt_db(const ushortT* __restrict__ A,
                                           const ushortT* __restrict__ W,
                                           const float* __restrict__ bias,
                                           void* __restrict__ C, float oscale,
                                           ushortT* __restrict__ As0,
                                           ushortT* __restrict__ As1,
                                           ushortT* __restrict__ Bs0,
                                           ushortT* __restrict__ Bs1) {
  constexpr int K = 1024, N = 1024;
  constexpr int NI = (NW == 4) ? 4 : 2;  // n-fragments per wave
  constexpr int CPT = 8 / NW;            // gl2lds chunks/thread per 32-tile
  constexpr int NT = K / 32;             // 32 K-steps
  const int tid = threadIdx.x;
  const int wave = tid >> 6, lane = tid & 63, quad = lane >> 4, l16 = lane & 15;
  const int wm = wave & 1, wn = wave >> 1;
  const int by = blockIdx.x, bx = blockIdx.y;

  const ushortT* Ab = A + (size_t)by * 128 * K;
  const ushortT* Wb = W + (size_t)bx * 128 * K;

  const f32x4 fz = {0.f, 0.f, 0.f, 0.f};
  f32x4 acc[4][NI];
#pragma unroll
  for (int mi = 0; mi < 4; mi++)
#pragma unroll
    for (int ni = 0; ni < NI; ni++) acc[mi][ni] = fz;

  // stage one [128][32] tile from src (row stride K) at column kt into dst
  auto stage = [&](const ushortT* src, int kt, ushortT* dst) {
#pragma unroll
    for (int i = 0; i < CPT; ++i) {
      const int cb = (wave * CPT + i) * 64;  // wave-uniform chunk base
      const int c = cb + lane;               // 16B chunk id, 512 per tile
      const int m = c >> 2, ko = c & 3;
      gl2lds16(src + (size_t)m * K + kt + ko * 8, dst + (size_t)cb * 8);
    }
  };
  // compute one 32-K step from staged tiles (identical to R11 body)
  auto compute = [&](const ushortT* As, const ushortT* Bs) {
    bf16x8 af[4], bfr[NI];
#pragma unroll
    for (int mi = 0; mi < 4; mi++)
      af[mi] = *(const bf16x8*)(As + (wm * 64 + mi * 16 + l16) * 32 + quad * 8);
#pragma unroll
    for (int ni = 0; ni < NI; ni++)
      bfr[ni] = *(const bf16x8*)(Bs + (wn * (NI * 16) + ni * 16 + l16) * 32 +
                                 quad * 8);
#pragma unroll
    for (int mi = 0; mi < 4; mi++)
#pragma unroll
      for (int ni = 0; ni < NI; ni++)
        acc[mi][ni] = mfma_bf16(af[mi], bfr[ni], acc[mi][ni]);
  };

  // prologue: fill buffer 0
  stage(Wb, 0, Bs0);
  stage(Ab, 0, As0);
  __syncthreads();  // drains prologue loads (compiler emits vmcnt(0))
  for (int t = 0; t < NT; ++t) {
    const bool odd = t & 1;
    if (t + 1 < NT) {  // issue next tile's loads BEFORE compute
      stage(Wb, (t + 1) * 32, odd ? Bs0 : Bs1);
      stage(Ab, (t + 1) * 32, odd ? As0 : As1);
    }
    compute(odd ? As1 : As0, odd ? Bs1 : Bs0);
    __syncthreads();  // drains stage(t+1); guards buffer reuse next iter
  }

  // epilogue: C/D layout col=l16, row=quad*4+i
#pragma unroll
  for (int mi = 0; mi < 4; mi++) {
    const int row0 = by * 128 + wm * 64 + mi * 16 + quad * 4;
#pragma unroll
    for (int ni = 0; ni < NI; ni++) {
      const int col = bx * 128 + wn * (NI * 16) + ni * 16 + l16;
      const float bv = HAS_BIAS ? bias[col] : 0.f;
      if (VT_MODE == 0) {
#pragma unroll
        for (int i = 0; i < 4; i++) {
          const size_t idx = (size_t)(row0 + i) * N + col;
          const float val = acc[mi][ni][i] * oscale + bv;
          if (OUT_F32)
            ((float*)C)[idx] = val;
          else
            ((ushortT*)C)[idx] = f2b(val);
        }
      } else {
        // store V as f16 (PV uses f16 MFMA)
        const int h = col >> 6, dd = col & 63;
        const int bb = row0 >> 11, s0 = row0 & (S_LEN - 1);
        u32x2 pk;
        pk[0] = __builtin_bit_cast(
            unsigned, __builtin_amdgcn_cvt_pkrtz(acc[mi][ni][0], acc[mi][ni][1]));
        pk[1] = __builtin_bit_cast(
            unsigned, __builtin_amdgcn_cvt_pkrtz(acc[mi][ni][2], acc[mi][ni][3]));
        *(u32x2*)((ushortT*)C + ((size_t)((bb * NH + h) * HD + dd) << 11) + s0) =
            pk;
      }
    }
  }
}

// fast path: all operands bf16, dbuf gl2lds staging
__global__ __launch_bounds__(256) void qkv_proj_bf16_kernel(
    const ushortT* __restrict__ xb, const ushortT* __restrict__ wcat,
    ushortT* __restrict__ qb, ushortT* __restrict__ kb,
    ushortT* __restrict__ vtb) {
  __shared__ alignas(16) ushortT As0[128 * 32];
  __shared__ alignas(16) ushortT As1[128 * 32];
  __shared__ alignas(16) ushortT Bs0[128 * 32];
  __shared__ alignas(16) ushortT Bs1[128 * 32];
  const size_t E = (size_t)MTOT * DMODEL;
  const int z = blockIdx.z;
  const float QSC = 1.44269504088896f / 32.0f;
  if (z == 0)
    gemm_bt_db<0, false, false, 4>(xb + 2 * E, wcat, nullptr, qb, QSC, As0,
                                   As1, Bs0, Bs1);
  else if (z == 1)
    gemm_bt_db<0, false, false, 4>(xb + E, wcat + WSZ, nullptr, kb, 1.0f, As0,
                                   As1, Bs0, Bs1);
  else
    gemm_bt_db<1, false, false, 4>(xb, wcat + 2 * WSZ, nullptr, vtb, 1.0f,
                                   As0, As1, Bs0, Bs1);
}

// fallback (R10 path, BK=32 single-buffer): A staged from f32 in-kernel.
__global__ __launch_bounds__(256) void qkv_proj_f32_kernel(
    const float* __restrict__ vals, const float* __restrict__ keys,
    const float* __restrict__ qry, const ushortT* __restrict__ wcat,
    ushortT* __restrict__ qb, ushortT* __restrict__ kb,
    ushortT* __restrict__ vtb) {
  __shared__ alignas(16) ushortT As[128 * 40];
  __shared__ alignas(16) ushortT Bs[128 * 32];
  const int z = blockIdx.z;
  const float QSC = 1.44269504088896f / 32.0f;
  const float* Asrc = (z == 0) ? qry : (z == 1) ? keys : vals;
  const ushortT* Wsrc = wcat + (size_t)(z == 0 ? 0 : (z == 1 ? 1 : 2)) * WSZ;
  const float oscale = (z == 0) ? QSC : 1.0f;

  constexpr int K = 1024, N = 1024;
  const int tid = threadIdx.x;
  const int wave = tid >> 6, lane = tid & 63, quad = lane >> 4, l16 = lane & 15;
  const int wm = wave & 1, wn = wave >> 1;
  const int by = blockIdx.x, bx = blockIdx.y;
  const size_t Aoff = (size_t)by * 128 * K;
  const ushortT* Wb = Wsrc + (size_t)bx * 128 * K;

  const f32x4 fz = {0.f, 0.f, 0.f, 0.f};
  f32x4 acc[4][4];
#pragma unroll
  for (int mi = 0; mi < 4; mi++)
#pragma unroll
    for (int ni = 0; ni < 4; ni++) acc[mi][ni] = fz;

  for (int kt = 0; kt < K; kt += 32) {
    __syncthreads();
#pragma unroll
    for (int i = 0; i < 2; ++i) {
      const int cb = (wave * 2 + i) * 64;
      const int c = cb + lane;
      const int m = c >> 2, ko = c & 3;
      gl2lds16(Wb + (size_t)m * K + kt + ko * 8, Bs + (size_t)cb * 8);
    }
#pragma unroll
    for (int j = 0; j < 2; ++j) {
      const int c = tid + j * 256;
      const int m = c >> 2, ko = c & 3;
      const float* ap = Asrc + Aoff + (size_t)m * K + kt + ko * 8;
      uint4 w0 = *(const uint4*)ap;
      uint4 w1 = *(const uint4*)(ap + 4);
      uint4 pk;
      pk.x = rne_pack(w0.x, w0.y);
      pk.y = rne_pack(w0.z, w0.w);
      pk.z = rne_pack(w1.x, w1.y);
      pk.w = rne_pack(w1.z, w1.w);
      *(uint4*)(As + (size_t)m * 40 + ko * 8) = pk;
    }
    __syncthreads();

    bf16x8 af[4], bfr[4];
#pragma unroll
    for (int mi = 0; mi < 4; mi++)
      af[mi] = *(const bf16x8*)(As + (wm * 64 + mi * 16 + l16) * 40 + quad * 8);
#pragma unroll
    for (int ni = 0; ni < 4; ni++)
      bfr[ni] = *(const bf16x8*)(Bs + (wn * 64 + ni * 16 + l16) * 32 + quad * 8);
#pragma unroll
    for (int mi = 0; mi < 4; mi++)
#pragma unroll
      for (int ni = 0; ni < 4; ni++)
        acc[mi][ni] = mfma_bf16(af[mi], bfr[ni], acc[mi][ni]);
  }

#pragma unroll
  for (int mi = 0; mi < 4; mi++) {
    const int row0 = by * 128 + wm * 64 + mi * 16 + quad * 4;
#pragma unroll
    for (int ni = 0; ni < 4; ni++) {
      const int col = bx * 128 + wn * 64 + ni * 16 + l16;
      if (z != 2) {
        ushortT* Cb = (z == 0) ? qb : kb;
#pragma unroll
        for (int i = 0; i < 4; i++)
          Cb[(size_t)(row0 + i) * N + col] = f2b(acc[mi][ni][i] * oscale);
      } else {
        const int h = col >> 6, dd = col & 63;
        const int bb = row0 >> 11, s0 = row0 & (S_LEN - 1);
        u32x2 pk;
        pk[0] = __builtin_bit_cast(
            unsigned, __builtin_amdgcn_cvt_pkrtz(acc[mi][ni][0], acc[mi][ni][1]));
        pk[1] = __builtin_bit_cast(
            unsigned, __builtin_amdgcn_cvt_pkrtz(acc[mi][ni][2], acc[mi][ni][3]));
        *(u32x2*)(vtb + ((size_t)((bb * NH + h) * HD + dd) << 11) + s0) = pk;
      }
    }
  }
}

// out-proj: 8 waves/block (proven R11), dbuf staging
__global__ __launch_bounds__(512) void out_proj_kernel(
    const ushortT* __restrict__ ain, const ushortT* __restrict__ wo,
    const float* __restrict__ bo, float* __restrict__ out) {
  __shared__ alignas(16) ushortT As0[128 * 32];
  __shared__ alignas(16) ushortT As1[128 * 32];
  __shared__ alignas(16) ushortT Bs0[128 * 32];
  __shared__ alignas(16) ushortT Bs1[128 * 32];
  gemm_bt_db<0, true, true, 8>(ain, wo, bo, out, 1.0f, As0, As1, Bs0, Bs1);
}

// ---------------------------------------------------------------------------
// Flash attention v2 (exact R10/R11 version, proven). Block = (b,h) x
// (q-tile 128); grid (64,16). S^T = K Q^T via operand-swapped bf16 MFMA;
// exp2(S^T) in C-layout feeds the k16 f16 MFMA's B operand. PV: O^T=V^T P^T.
// LDS: Ks 128x72 bf16 + Vts 64x136 f16 = 35 KB.
// ---------------------------------------------------------------------------
__global__ __launch_bounds__(256) void attn_kernel(
    const ushortT* __restrict__ qb, const ushortT* __restrict__ kb,
    const ushortT* __restrict__ vtb, ushortT* __restrict__ ab) {
  __shared__ alignas(16) ushortT Ks[128 * 72];   // K: [kv][d] bf16, stride 72
  __shared__ alignas(16) ushortT Vts[64 * 136];  // V^T: [d][kv] f16, stride 136

  const int tid = threadIdx.x;
  const int wave = tid >> 6, lane = tid & 63, quad = lane >> 4, l16 = lane & 15;
  const int bh = blockIdx.x, qt = blockIdx.y, b = bh >> 4, h = bh & 15;

  bf16x8 qf[2][2];
#pragma unroll
  for (int mi = 0; mi < 2; mi++)
#pragma unroll
    for (int kq = 0; kq < 2; kq++) {
      const int qrow = qt * 128 + wave * 32 + mi * 16 + l16;
      qf[mi][kq] = *(const bf16x8*)(qb + (size_t)(b * S_LEN + qrow) * DMODEL +
                                    h * HD + kq * 32 + quad * 8);
    }

  const f32x4 fz = {0.f, 0.f, 0.f, 0.f};
  f32x4 osum[4][2];
#pragma unroll
  for (int ni = 0; ni < 4; ni++)
#pragma unroll
    for (int mi = 0; mi < 2; mi++) osum[ni][mi] = fz;
  float lsum[2] = {0.f, 0.f};

  us8 kreg[4], vreg[4];
  auto issue_loads = [&](int t) {
#pragma unroll
    for (int p = 0; p < 4; p++) {
      const int r = (tid >> 3) + p * 32, c = (tid & 7) * 8;
      kreg[p] = *(const us8*)(kb + (size_t)(b * S_LEN + t * 128 + r) * DMODEL +
                              h * HD + c);
    }
#pragma unroll
    for (int p = 0; p < 4; p++) {
      const int r = (tid >> 4) + p * 16, c = (tid & 15) * 8;
      vreg[p] = *(const us8*)(vtb + (size_t)((b * NH + h) * HD + r) * S_LEN +
                              t * 128 + c);
    }
  };
  issue_loads(0);

  for (int t = 0; t < 16; ++t) {
    __syncthreads();
#pragma unroll
    for (int p = 0; p < 4; p++) {
      const int r = (tid >> 3) + p * 32, c = (tid & 7) * 8;
      *(us8*)(Ks + r * 72 + c) = kreg[p];
    }
#pragma unroll
    for (int p = 0; p < 4; p++) {
      const int r = (tid >> 4) + p * 16, c = (tid & 15) * 8;
      *(us8*)(Vts + r * 136 + c) = vreg[p];
    }
    if (t < 15) issue_loads(t + 1);
    __syncthreads();

#pragma unroll
    for (int h2 = 0; h2 < 2; ++h2) {
      f32x4 sacc[4][2];
#pragma unroll
      for (int mt = 0; mt < 4; mt++)
#pragma unroll
        for (int mi = 0; mi < 2; mi++) sacc[mt][mi] = fz;
      __builtin_amdgcn_s_setprio(1);
#pragma unroll
      for (int kq = 0; kq < 2; kq++)
#pragma unroll
        for (int mt = 0; mt < 4; mt++) {
          bf16x8 kf = *(const bf16x8*)(Ks + ((h2 * 4 + mt) * 16 + l16) * 72 +
                                       kq * 32 + quad * 8);
#pragma unroll
          for (int mi = 0; mi < 2; mi++)
            sacc[mt][mi] = mfma_bf16(kf, qf[mi][kq], sacc[mt][mi]);
        }
      __builtin_amdgcn_s_setprio(0);

      u32x2 pf[4][2];
#pragma unroll
      for (int mt = 0; mt < 4; mt++)
#pragma unroll
        for (int mi = 0; mi < 2; mi++) {
          const float e0 = __builtin_amdgcn_exp2f(sacc[mt][mi][0]);
          const float e1 = __builtin_amdgcn_exp2f(sacc[mt][mi][1]);
          const float e2 = __builtin_amdgcn_exp2f(sacc[mt][mi][2]);
          const float e3 = __builtin_amdgcn_exp2f(sacc[mt][mi][3]);
          lsum[mi] += (e0 + e1) + (e2 + e3);
          pf[mt][mi][0] =
              __builtin_bit_cast(unsigned, __builtin_amdgcn_cvt_pkrtz(e0, e1));
          pf[mt][mi][1] =
              __builtin_bit_cast(unsigned, __builtin_amdgcn_cvt_pkrtz(e2, e3));
        }

      __builtin_amdgcn_s_setprio(1);
#pragma unroll
      for (int s = 0; s < 4; ++s)
#pragma unroll
        for (int ni = 0; ni < 4; ni++) {
          f16x4 vf = *(const f16x4*)(Vts + (ni * 16 + l16) * 136 +
                                     (h2 * 4 + s) * 16 + quad * 4);
#pragma unroll
          for (int mi = 0; mi < 2; mi++)
            osum[ni][mi] =
                mfma16_f16(vf, __builtin_bit_cast(f16x4, pf[s][mi]), osum[ni][mi]);
        }
      __builtin_amdgcn_s_setprio(0);
    }
  }

#pragma unroll
  for (int mi = 0; mi < 2; mi++) {
    float s = lsum[mi];
    s += __shfl_xor(s, 16, 64);
    s += __shfl_xor(s, 32, 64);
    lsum[mi] = 1.0f / s;
  }

#pragma unroll
  for (int mi = 0; mi < 2; mi++) {
    const int qrow = qt * 128 + wave * 32 + mi * 16 + l16;
#pragma unroll
    for (int ni = 0; ni < 4; ni++) {
      us4 pk;
#pragma unroll
      for (int i = 0; i < 4; i++) pk[i] = f2b(osum[ni][mi][i] * lsum[mi]);
      *(us4*)(ab + (size_t)(b * S_LEN + qrow) * DMODEL + h * HD + ni * 16 +
              quad * 4) = pk;
    }
  }
}

// ---------------------------------------------------------------------------
extern "C" void kernel_launch(void* const* d_in, const int* in_sizes, int n_in,
                              void* d_out, int out_size, void* d_ws,
                              size_t ws_size, hipStream_t stream) {
  const float* vals = (const float*)d_in[0];
  const float* keys = (const float*)d_in[1];
  const float* qry = (const float*)d_in[2];
  const float* Wv = (const float*)d_in[3];
  const float* Wk = (const float*)d_in[4];
  const float* Wq = (const float*)d_in[5];
  const float* Wo = (const float*)d_in[6];
  const float* bo = (const float*)d_in[7];
  float* out = (float*)d_out;

  ushortT* ws = (ushortT*)d_ws;
  const size_t E = (size_t)MTOT * DMODEL;  // 8,388,608 elements
  ushortT* qbuf = ws;                      // scaled Q proj; reused as attn out
  ushortT* kbuf = ws + E;
  ushortT* vtb = ws + 2 * E;               // (B,H,64,S) transposed V, f16
  ushortT* wcat = ws + 3 * E;              // wq|wk|wv|wo, bf16, WSZ each
  ushortT* xb = ws + 3 * E + 4 * (size_t)WSZ;  // vals|keys|qry bf16, E each
  ushortT* abuf = qbuf;                    // attention out aliases Q (safe)

  const size_t need = (6 * E + 4 * (size_t)WSZ) * sizeof(ushortT);

  dim3 blk(256, 1, 1);
  convert_w_kernel<<<dim3(512, 4), blk, 0, stream>>>(Wq, Wk, Wv, Wo, wcat);
  if (ws_size >= need) {
    convert_x_kernel<<<dim3(4096, 3), blk, 0, stream>>>(vals, keys, qry, xb);
    qkv_proj_bf16_kernel<<<dim3(64, 8, 3), blk, 0, stream>>>(xb, wcat, qbuf,
                                                             kbuf, vtb);
  } else {
    qkv_proj_f32_kernel<<<dim3(64, 8, 3), blk, 0, stream>>>(vals, keys, qry,
                                                            wcat, qbuf, kbuf,
                                                            vtb);
  }
  attn_kernel<<<dim3(64, 16), blk, 0, stream>>>(qbuf, kbuf, vtb, abuf);
  out_proj_kernel<<<dim3(64, 8), dim3(512, 1, 1), 0, stream>>>(
      abuf, wcat + 3 * WSZ, bo, out);
}

// Round 9
// 339.890 us; speedup vs baseline: 1.0487x; 1.0487x over previous
//
#include <hip/hip_runtime.h>
#include <cstdint>
#include <cstddef>

// ---------------------------------------------------------------------------
// MultiHeadSelfAttention: B=4, S=2048, D=1024, H=16, Hd=64. f32 in/out.
// R14: base = exact R11 (best, 344.3 µs). GEMM pipeline experiments closed
// (R12/R13 both regressed — TLP already hides staging at 5-6 blocks/CU).
// Single change: attention K/V staging moves to global_load_lds with
// XOR-swizzled per-lane SOURCE addresses + linear LDS dest + same-XOR reads
// (rule-21 / m201 pattern). Removes kreg/vreg (-32 VGPR), 8 ds_write_b128
// and the issue_loads VALU from the per-tile critical path. LDS 35->32 KB.
// ---------------------------------------------------------------------------

typedef unsigned short ushortT;
typedef __bf16 bf16x8 __attribute__((ext_vector_type(8)));
typedef _Float16 f16x4 __attribute__((ext_vector_type(4)));
typedef float f32x4 __attribute__((ext_vector_type(4)));
typedef unsigned int u32x2 __attribute__((ext_vector_type(2)));
typedef unsigned short us4 __attribute__((ext_vector_type(4)));
typedef unsigned short us8 __attribute__((ext_vector_type(8)));

#define S_LEN 2048
#define NB 4
#define NH 16
#define HD 64
#define DMODEL 1024
#define MTOT 8192   // NB * S_LEN
#define WSZ 1048576 // DMODEL * DMODEL

#define AS1 __attribute__((address_space(1)))
#define AS3 __attribute__((address_space(3)))

__device__ __forceinline__ ushortT f2b(float f) {  // round-to-nearest-even
  unsigned x = __builtin_bit_cast(unsigned, f);
  x += 0x7fffu + ((x >> 16) & 1u);
  return (ushortT)(x >> 16);
}

// pack two f32 (bit patterns) -> two RNE bf16 in one dword (lo in low half)
__device__ __forceinline__ unsigned rne_pack(unsigned lo, unsigned hi) {
  lo += 0x7fffu + ((lo >> 16) & 1u);
  hi += 0x7fffu + ((hi >> 16) & 1u);
  return __builtin_amdgcn_perm(hi, lo, 0x07060302u);
}

__device__ __forceinline__ f32x4 mfma_bf16(bf16x8 a, bf16x8 b, f32x4 c) {
  return __builtin_amdgcn_mfma_f32_16x16x32_bf16(a, b, c, 0, 0, 0);
}
__device__ __forceinline__ f32x4 mfma16_f16(f16x4 a, f16x4 b, f32x4 c) {
  return __builtin_amdgcn_mfma_f32_16x16x16f16(a, b, c, 0, 0, 0);
}

// async 16B global->LDS; lds dst is wave-uniform base, lane i lands at +16*i;
// the GLOBAL source address is per-lane (gather DMA).
__device__ __forceinline__ void gl2lds16(const ushortT* g, ushortT* l) {
  __builtin_amdgcn_global_load_lds((const AS1 void*)g, (AS3 void*)l, 16, 0, 0);
}

// ---------------------------------------------------------------------------
// f32 -> bf16 converters (elementwise, 8 elems/thread).
// ---------------------------------------------------------------------------
__global__ __launch_bounds__(256) void convert_w_kernel(
    const float* __restrict__ wq, const float* __restrict__ wk,
    const float* __restrict__ wv, const float* __restrict__ wo,
    ushortT* __restrict__ dst) {
  const float* s;
  switch (blockIdx.y) {
    case 0: s = wq; break;
    case 1: s = wk; break;
    case 2: s = wv; break;
    default: s = wo; break;
  }
  ushortT* d = dst + (size_t)blockIdx.y * WSZ;
  const size_t i = ((size_t)blockIdx.x * 256 + threadIdx.x) * 8;
  uint4 w0 = *(const uint4*)(s + i);
  uint4 w1 = *(const uint4*)(s + i + 4);
  uint4 pk;
  pk.x = rne_pack(w0.x, w0.y);
  pk.y = rne_pack(w0.z, w0.w);
  pk.z = rne_pack(w1.x, w1.y);
  pk.w = rne_pack(w1.z, w1.w);
  *(uint4*)(d + i) = pk;
}

__global__ __launch_bounds__(256) void convert_x_kernel(
    const float* __restrict__ vals, const float* __restrict__ keys,
    const float* __restrict__ qry, ushortT* __restrict__ dst) {
  const float* s;
  switch (blockIdx.y) {
    case 0: s = vals; break;
    case 1: s = keys; break;
    default: s = qry; break;
  }
  ushortT* d = dst + (size_t)blockIdx.y * ((size_t)MTOT * DMODEL);
  const size_t i = ((size_t)blockIdx.x * 256 + threadIdx.x) * 8;
  uint4 w0 = *(const uint4*)(s + i);
  uint4 w1 = *(const uint4*)(s + i + 4);
  uint4 pk;
  pk.x = rne_pack(w0.x, w0.y);
  pk.y = rne_pack(w0.z, w0.w);
  pk.z = rne_pack(w1.x, w1.y);
  pk.w = rne_pack(w1.z, w1.w);
  *(uint4*)(d + i) = pk;
}

// ---------------------------------------------------------------------------
// GEMM tile (exact R11): C(M,N) = A(M,K) * W(N,K)^T (+bias). Grid (64,8[,z]):
// by = blockIdx.x (A row panel), bx = blockIdx.y (W col panel) so all 8
// bx-blocks of a panel share one XCD's L2 (linear%8 == by%8).
// NW = waves/block (4: 2x2 of 64x64 subtiles; 8: 2x4 of 64x32 subtiles).
// A_F32 (NW=4 only): per-lane f32 loads + rne_pack + ds_write (proven).
// ASTR: LDS row stride for A tile (gl2lds path requires 32).
// VT_MODE=1: scatter-store f16 into Vt layout (B,H,64,S), 4-wide along S.
// ---------------------------------------------------------------------------
template <int VT_MODE, bool A_F32, bool OUT_F32, bool HAS_BIAS, int ASTR,
          int NW>
__device__ __forceinline__ void gemm_bt_tile(const void* __restrict__ A,
                                             const ushortT* __restrict__ W,
                                             const float* __restrict__ bias,
                                             void* __restrict__ C, float oscale,
                                             ushortT* __restrict__ As,
                                             ushortT* __restrict__ Bs) {
  constexpr int K = 1024, N = 1024;
  constexpr int NI = (NW == 4) ? 4 : 2;   // n-fragments per wave
  constexpr int CPT = 8 / NW;             // gl2lds chunks per thread per tile
  static_assert(!A_F32 || NW == 4, "f32 A staging implemented for 4 waves");
  static_assert(A_F32 || ASTR == 32, "gl2lds A staging requires linear rows");
  const int tid = threadIdx.x;
  const int wave = tid >> 6, lane = tid & 63, quad = lane >> 4, l16 = lane & 15;
  const int wm = wave & 1, wn = wave >> 1;
  const int by = blockIdx.x, bx = blockIdx.y;  // swizzled roles

  const size_t Aoff = (size_t)by * 128 * K;
  const ushortT* Wb = W + (size_t)bx * 128 * K;

  const f32x4 fz = {0.f, 0.f, 0.f, 0.f};
  f32x4 acc[4][NI];
#pragma unroll
  for (int mi = 0; mi < 4; mi++)
#pragma unroll
    for (int ni = 0; ni < NI; ni++) acc[mi][ni] = fz;

  for (int kt = 0; kt < K; kt += 32) {
    __syncthreads();  // previous iteration's LDS reads done
    // W tile: async 16B direct-to-LDS
#pragma unroll
    for (int i = 0; i < CPT; ++i) {
      const int cb = (wave * CPT + i) * 64;  // wave-uniform chunk base
      const int c = cb + lane;               // 16B chunk id, 512 per tile
      const int m = c >> 2, ko = c & 3;
      gl2lds16(Wb + (size_t)m * K + kt + ko * 8, Bs + (size_t)cb * 8);
    }
    // A tile
    if (A_F32) {
#pragma unroll
      for (int j = 0; j < 2; ++j) {
        const int c = tid + j * 256;
        const int m = c >> 2, ko = c & 3;
        const float* ap = (const float*)A + Aoff + (size_t)m * K + kt + ko * 8;
        uint4 w0 = *(const uint4*)ap;
        uint4 w1 = *(const uint4*)(ap + 4);
        uint4 pk;
        pk.x = rne_pack(w0.x, w0.y);
        pk.y = rne_pack(w0.z, w0.w);
        pk.z = rne_pack(w1.x, w1.y);
        pk.w = rne_pack(w1.z, w1.w);
        *(uint4*)(As + (size_t)m * ASTR + ko * 8) = pk;
      }
    } else {
#pragma unroll
      for (int i = 0; i < CPT; ++i) {
        const int cb = (wave * CPT + i) * 64;
        const int c = cb + lane;
        const int m = c >> 2, ko = c & 3;
        gl2lds16((const ushortT*)A + Aoff + (size_t)m * K + kt + ko * 8,
                 As + (size_t)cb * 8);
      }
    }
    __syncthreads();  // staged data visible

    bf16x8 af[4], bfr[NI];
#pragma unroll
    for (int mi = 0; mi < 4; mi++)
      af[mi] =
          *(const bf16x8*)(As + (wm * 64 + mi * 16 + l16) * ASTR + quad * 8);
#pragma unroll
    for (int ni = 0; ni < NI; ni++)
      bfr[ni] = *(const bf16x8*)(Bs + (wn * (NI * 16) + ni * 16 + l16) * 32 +
                                 quad * 8);
#pragma unroll
    for (int mi = 0; mi < 4; mi++)
#pragma unroll
      for (int ni = 0; ni < NI; ni++)
        acc[mi][ni] = mfma_bf16(af[mi], bfr[ni], acc[mi][ni]);
  }

  // epilogue: C/D layout col=l16, row=quad*4+i
#pragma unroll
  for (int mi = 0; mi < 4; mi++) {
    const int row0 = by * 128 + wm * 64 + mi * 16 + quad * 4;
#pragma unroll
    for (int ni = 0; ni < NI; ni++) {
      const int col = bx * 128 + wn * (NI * 16) + ni * 16 + l16;
      const float bv = HAS_BIAS ? bias[col] : 0.f;
      if (VT_MODE == 0) {
#pragma unroll
        for (int i = 0; i < 4; i++) {
          const size_t idx = (size_t)(row0 + i) * N + col;
          const float val = acc[mi][ni][i] * oscale + bv;
          if (OUT_F32)
            ((float*)C)[idx] = val;
          else
            ((ushortT*)C)[idx] = f2b(val);
        }
      } else {
        // store V as f16 (PV uses f16 MFMA)
        const int h = col >> 6, dd = col & 63;
        const int bb = row0 >> 11, s0 = row0 & (S_LEN - 1);
        u32x2 pk;
        pk[0] = __builtin_bit_cast(
            unsigned, __builtin_amdgcn_cvt_pkrtz(acc[mi][ni][0], acc[mi][ni][1]));
        pk[1] = __builtin_bit_cast(
            unsigned, __builtin_amdgcn_cvt_pkrtz(acc[mi][ni][2], acc[mi][ni][3]));
        *(u32x2*)((ushortT*)C + ((size_t)((bb * NH + h) * HD + dd) << 11) + s0) =
            pk;
      }
    }
  }
}

// fast path: all operands bf16, pure gl2lds staging
__global__ __launch_bounds__(256) void qkv_proj_bf16_kernel(
    const ushortT* __restrict__ xb, const ushortT* __restrict__ wcat,
    ushortT* __restrict__ qb, ushortT* __restrict__ kb,
    ushortT* __restrict__ vtb) {
  __shared__ alignas(16) ushortT As[128 * 32];
  __shared__ alignas(16) ushortT Bs[128 * 32];
  const size_t E = (size_t)MTOT * DMODEL;
  const int z = blockIdx.z;
  const float QSC = 1.44269504088896f / 32.0f;
  if (z == 0)
    gemm_bt_tile<0, false, false, false, 32, 4>(xb + 2 * E, wcat, nullptr, qb,
                                                QSC, As, Bs);
  else if (z == 1)
    gemm_bt_tile<0, false, false, false, 32, 4>(xb + E, wcat + WSZ, nullptr,
                                                kb, 1.0f, As, Bs);
  else
    gemm_bt_tile<1, false, false, false, 32, 4>(xb, wcat + 2 * WSZ, nullptr,
                                                vtb, 1.0f, As, Bs);
}

// fallback (R10 path): A staged from f32 in-kernel
__global__ __launch_bounds__(256) void qkv_proj_kernel(
    const float* __restrict__ vals, const float* __restrict__ keys,
    const float* __restrict__ qry, const ushortT* __restrict__ wcat,
    ushortT* __restrict__ qb, ushortT* __restrict__ kb,
    ushortT* __restrict__ vtb) {
  __shared__ alignas(16) ushortT As[128 * 40];
  __shared__ alignas(16) ushortT Bs[128 * 32];
  const int z = blockIdx.z;
  const float QSC = 1.44269504088896f / 32.0f;
  if (z == 0)
    gemm_bt_tile<0, true, false, false, 40, 4>(qry, wcat, nullptr, qb, QSC, As,
                                               Bs);
  else if (z == 1)
    gemm_bt_tile<0, true, false, false, 40, 4>(keys, wcat + WSZ, nullptr, kb,
                                               1.0f, As, Bs);
  else
    gemm_bt_tile<1, true, false, false, 40, 4>(vals, wcat + 2 * WSZ, nullptr,
                                               vtb, 1.0f, As, Bs);
}

// out-proj: 8 waves/block (512 thr) for 16 waves/CU at 2 blocks/CU
__global__ __launch_bounds__(512) void out_proj_kernel(
    const ushortT* __restrict__ ain, const ushortT* __restrict__ wo,
    const float* __restrict__ bo, float* __restrict__ out) {
  __shared__ alignas(16) ushortT As[128 * 32];
  __shared__ alignas(16) ushortT Bs[128 * 32];
  gemm_bt_tile<0, false, true, true, 32, 8>(ain, wo, bo, out, 1.0f, As, Bs);
}

// ---------------------------------------------------------------------------
// Flash attention v2. Block = (b,h) x (q-tile 128); grid (64,16). Math and
// fragment layouts identical to the proven R10/R11 kernel. R14 change: K/V
// staged via global_load_lds into LINEAR LDS with XOR-swizzled per-lane
// global sources; reads apply the same XOR.
//   Ks  [128][64] bf16: 16B chunk p at row r holds logical chunk p^(r&7).
//   Vts [64][128] f16 : 16B chunk p at row r holds logical chunk p^(r&15).
// LDS: 16 KB + 16 KB = 32 KB. 2 barriers/tile.
// ---------------------------------------------------------------------------
__global__ __launch_bounds__(256) void attn_kernel(
    const ushortT* __restrict__ qb, const ushortT* __restrict__ kb,
    const ushortT* __restrict__ vtb, ushortT* __restrict__ ab) {
  __shared__ alignas(16) ushortT Ks[128 * 64];   // K: [kv][d] bf16, swizzled
  __shared__ alignas(16) ushortT Vts[64 * 128];  // V^T: [d][kv] f16, swizzled

  const int tid = threadIdx.x;
  const int wave = tid >> 6, lane = tid & 63, quad = lane >> 4, l16 = lane & 15;
  const int bh = blockIdx.x, qt = blockIdx.y, b = bh >> 4, h = bh & 15;

  // Q fragments (A-layout bytes == B-layout of Q^T): rows wave*32+mi*16+l16
  bf16x8 qf[2][2];
#pragma unroll
  for (int mi = 0; mi < 2; mi++)
#pragma unroll
    for (int kq = 0; kq < 2; kq++) {
      const int qrow = qt * 128 + wave * 32 + mi * 16 + l16;
      qf[mi][kq] = *(const bf16x8*)(qb + (size_t)(b * S_LEN + qrow) * DMODEL +
                                    h * HD + kq * 32 + quad * 8);
    }

  const f32x4 fz = {0.f, 0.f, 0.f, 0.f};
  f32x4 osum[4][2];  // O^T: [d-tile][q-tile], row=d=quad*4+i, col=q=l16
#pragma unroll
  for (int ni = 0; ni < 4; ni++)
#pragma unroll
    for (int mi = 0; mi < 2; mi++) osum[ni][mi] = fz;
  float lsum[2] = {0.f, 0.f};  // per-lane partial row sums (q = mi*16+l16)

  const ushortT* kbb = kb + (size_t)b * S_LEN * DMODEL + h * HD;
  const ushortT* vbb = vtb + (size_t)(b * NH + h) * HD * S_LEN;

  for (int t = 0; t < 16; ++t) {
    __syncthreads();  // prior tile's Ks/Vts reads done
    // K tile: 1024 chunks, 4/thread; source column pre-swizzled by row
#pragma unroll
    for (int i = 0; i < 4; ++i) {
      const int cb = (wave * 4 + i) * 64;
      const int c = cb + lane;
      const int r = c >> 3, lch = (c & 7) ^ (r & 7);
      gl2lds16(kbb + (size_t)(t * 128 + r) * DMODEL + lch * 8, Ks + cb * 8);
    }
    // V tile: 1024 chunks, 4/thread; source column pre-swizzled by row
#pragma unroll
    for (int i = 0; i < 4; ++i) {
      const int cb = (wave * 4 + i) * 64;
      const int c = cb + lane;
      const int r = c >> 4, lch = (c & 15) ^ (r & 15);
      gl2lds16(vbb + (size_t)r * S_LEN + t * 128 + lch * 8, Vts + cb * 8);
    }
    __syncthreads();  // staged tiles visible (drains gl2lds)

    // two kv-halves of 64 to cap live registers
#pragma unroll
    for (int h2 = 0; h2 < 2; ++h2) {
      // S^T = K Q^T : A-frag from Ks (kv rows), B-frag = qf bytes
      f32x4 sacc[4][2];
#pragma unroll
      for (int mt = 0; mt < 4; mt++)
#pragma unroll
        for (int mi = 0; mi < 2; mi++) sacc[mt][mi] = fz;
      __builtin_amdgcn_s_setprio(1);
#pragma unroll
      for (int kq = 0; kq < 2; kq++)
#pragma unroll
        for (int mt = 0; mt < 4; mt++) {
          const int krow = (h2 * 4 + mt) * 16 + l16;
          const int kch = (kq * 4 + quad) ^ (krow & 7);
          bf16x8 kf = *(const bf16x8*)(Ks + krow * 64 + kch * 8);
#pragma unroll
          for (int mi = 0; mi < 2; mi++)
            sacc[mt][mi] = mfma_bf16(kf, qf[mi][kq], sacc[mt][mi]);
        }
      __builtin_amdgcn_s_setprio(0);

      // p = exp2(s); pack to f16 pairs (B-frag of k16 MFMA); row partials
      u32x2 pf[4][2];
#pragma unroll
      for (int mt = 0; mt < 4; mt++)
#pragma unroll
        for (int mi = 0; mi < 2; mi++) {
          const float e0 = __builtin_amdgcn_exp2f(sacc[mt][mi][0]);
          const float e1 = __builtin_amdgcn_exp2f(sacc[mt][mi][1]);
          const float e2 = __builtin_amdgcn_exp2f(sacc[mt][mi][2]);
          const float e3 = __builtin_amdgcn_exp2f(sacc[mt][mi][3]);
          lsum[mi] += (e0 + e1) + (e2 + e3);
          pf[mt][mi][0] =
              __builtin_bit_cast(unsigned, __builtin_amdgcn_cvt_pkrtz(e0, e1));
          pf[mt][mi][1] =
              __builtin_bit_cast(unsigned, __builtin_amdgcn_cvt_pkrtz(e2, e3));
        }

      // O^T += V^T P^T : A-frag from Vts (f16, swizzled), B-frag = pf
      __builtin_amdgcn_s_setprio(1);
#pragma unroll
      for (int s = 0; s < 4; ++s)
#pragma unroll
        for (int ni = 0; ni < 4; ni++) {
          const int vrow = ni * 16 + l16;
          const int vch = ((h2 * 4 + s) * 2 + (quad >> 1)) ^ (vrow & 15);
          f16x4 vf = *(const f16x4*)(Vts + vrow * 128 + vch * 8 +
                                     (quad & 1) * 4);
#pragma unroll
          for (int mi = 0; mi < 2; mi++)
            osum[ni][mi] =
                mfma16_f16(vf, __builtin_bit_cast(f16x4, pf[s][mi]), osum[ni][mi]);
        }
      __builtin_amdgcn_s_setprio(0);
    }
  }

  // complete row sums across the 4 quads holding each q column
#pragma unroll
  for (int mi = 0; mi < 2; mi++) {
    float s = lsum[mi];
    s += __shfl_xor(s, 16, 64);
    s += __shfl_xor(s, 32, 64);
    lsum[mi] = 1.0f / s;
  }

  // store O (bf16) into ab: lane holds O^T col q=l16, rows d=ni*16+quad*4+i
#pragma unroll
  for (int mi = 0; mi < 2; mi++) {
    const int qrow = qt * 128 + wave * 32 + mi * 16 + l16;
#pragma unroll
    for (int ni = 0; ni < 4; ni++) {
      us4 pk;
#pragma unroll
      for (int i = 0; i < 4; i++) pk[i] = f2b(osum[ni][mi][i] * lsum[mi]);
      *(us4*)(ab + (size_t)(b * S_LEN + qrow) * DMODEL + h * HD + ni * 16 +
              quad * 4) = pk;
    }
  }
}

// ---------------------------------------------------------------------------
extern "C" void kernel_launch(void* const* d_in, const int* in_sizes, int n_in,
                              void* d_out, int out_size, void* d_ws,
                              size_t ws_size, hipStream_t stream) {
  const float* vals = (const float*)d_in[0];
  const float* keys = (const float*)d_in[1];
  const float* qry = (const float*)d_in[2];
  const float* Wv = (const float*)d_in[3];
  const float* Wk = (const float*)d_in[4];
  const float* Wq = (const float*)d_in[5];
  const float* Wo = (const float*)d_in[6];
  const float* bo = (const float*)d_in[7];
  float* out = (float*)d_out;

  ushortT* ws = (ushortT*)d_ws;
  const size_t E = (size_t)MTOT * DMODEL;  // 8,388,608 elements
  ushortT* qbuf = ws;                      // scaled Q proj; reused as attn out
  ushortT* kbuf = ws + E;
  ushortT* vtb = ws + 2 * E;               // (B,H,64,S) transposed V, f16
  ushortT* wcat = ws + 3 * E;              // wq|wk|wv|wo, bf16, WSZ each
  ushortT* xb = ws + 3 * E + 4 * (size_t)WSZ;  // vals|keys|qry bf16, E each
  ushortT* abuf = qbuf;                    // attention out aliases Q (safe)

  const size_t need = (6 * E + 4 * (size_t)WSZ) * sizeof(ushortT);

  dim3 blk(256, 1, 1);
  convert_w_kernel<<<dim3(512, 4), blk, 0, stream>>>(Wq, Wk, Wv, Wo, wcat);
  if (ws_size >= need) {
    convert_x_kernel<<<dim3(4096, 3), blk, 0, stream>>>(vals, keys, qry, xb);
    qkv_proj_bf16_kernel<<<dim3(64, 8, 3), blk, 0, stream>>>(xb, wcat, qbuf,
                                                             kbuf, vtb);
  } else {
    qkv_proj_kernel<<<dim3(64, 8, 3), blk, 0, stream>>>(vals, keys, qry, wcat,
                                                        qbuf, kbuf, vtb);
  }
  attn_kernel<<<dim3(64, 16), blk, 0, stream>>>(qbuf, kbuf, vtb, abuf);
  out_proj_kernel<<<dim3(64, 8), dim3(512, 1, 1), 0, stream>>>(
      abuf, wcat + 3 * WSZ, bo, out);
}